// Round 5
// baseline (408.695 us; speedup 1.0000x reference)
//
#include <hip/hip_runtime.h>
#include <hip/hip_bf16.h>

typedef __attribute__((ext_vector_type(8))) short bf16x8;
typedef __attribute__((ext_vector_type(4))) float f32x4;

#define T_SEQ   512
#define B_BATCH 128
#define H_DIM   64
#define MB      32               // rows (t*B+b) per block
#define AS_STRIDE 136            // bf16 per row of A split-plane (128 + 8 pad)
#define ZS_STRIDE 193            // f32 per row of z tile (192 + 1 pad)
#define HS_STRIDE 68             // f32 per row of h tile (64 + 4 pad)
#define LASTROW ((T_SEQ - 1) * B_BATCH)   // 65408

// ws layout (shorts): W0 gate-rows (192x512) planes h/m/l, then W1 (192x64) h/m/l
#define W0H 0
#define W0M 98304
#define W0L 196608
#define W1H 294912
#define W1M 307200
#define W1L 319488
// total 331776 shorts = 663552 bytes of d_ws

// truncation 3-way split: f = h + m + l + r, |r| <= ~2^-24 |f|; subtractions exact
__device__ __forceinline__ void tsplit(float f, unsigned& h, unsigned& m, unsigned& l) {
    unsigned uf = __builtin_bit_cast(unsigned, f);
    h = uf >> 16;
    float hf = __builtin_bit_cast(float, uf & 0xFFFF0000u);
    float r1 = f - hf;
    unsigned u1 = __builtin_bit_cast(unsigned, r1);
    m = u1 >> 16;
    float mf = __builtin_bit_cast(float, u1 & 0xFFFF0000u);
    float r2 = r1 - mf;
    l = __builtin_bit_cast(unsigned, r2) >> 16;
}

__device__ __forceinline__ void tsplit2(float a, float b,
                                        unsigned& ph, unsigned& pm, unsigned& pl) {
    unsigned ha, ma, la, hb, mb, lb;
    tsplit(a, ha, ma, la);
    tsplit(b, hb, mb, lb);
    ph = ha | (hb << 16);
    pm = ma | (mb << 16);
    pl = la | (lb << 16);
}

// 6-product accumulate: (h1+m1+l1)(h2+m2+l2), dropping ml, lm, ll (~2^-24 |ab|)
__device__ __forceinline__ f32x4 mfma6(bf16x8 ah, bf16x8 am, bf16x8 al,
                                       bf16x8 bh, bf16x8 bm, bf16x8 bl, f32x4 c) {
    c = __builtin_amdgcn_mfma_f32_16x16x32_bf16(ah, bh, c, 0, 0, 0);
    c = __builtin_amdgcn_mfma_f32_16x16x32_bf16(ah, bm, c, 0, 0, 0);
    c = __builtin_amdgcn_mfma_f32_16x16x32_bf16(am, bh, c, 0, 0, 0);
    c = __builtin_amdgcn_mfma_f32_16x16x32_bf16(ah, bl, c, 0, 0, 0);
    c = __builtin_amdgcn_mfma_f32_16x16x32_bf16(al, bh, c, 0, 0, 0);
    c = __builtin_amdgcn_mfma_f32_16x16x32_bf16(am, bm, c, 0, 0, 0);
    return c;
}

// accurate sigmoid: libm expf + rcp with one Newton step
__device__ __forceinline__ float acc_sigmoid(float x) {
    float e = expf(-x);
    float d = 1.0f + e;
    float r = __builtin_amdgcn_rcpf(d);
    r = r * (2.0f - d * r);
    return r;
}

// inclusive prefix-product across the 64-lane wave (6-step scan)
__device__ __forceinline__ float scan_prod(float v, int lane) {
    for (int d = 1; d < 64; d <<= 1) {
        float t = __shfl_up(v, d);
        v *= (lane >= d) ? t : 1.0f;
    }
    return v;
}

// full 64-lane sum (butterfly)
__device__ __forceinline__ float wave_sum(float v) {
    for (int d = 1; d < 64; d <<= 1) v += __shfl_xor(v, d);
    return v;
}

// ---------- kernel 1: pre-split weights into d_ws ----------
__global__ __launch_bounds__(256) void presplit_w(const float* __restrict__ W0,
                                                  const float* __restrict__ W1,
                                                  short* __restrict__ ws) {
    int i = blockIdx.x * 256 + threadIdx.x;
    if (i < 98304) {                      // W0 gates 1..3: flat rows 64..255, stride 576
        int r = i >> 9, k = i & 511;
        unsigned h, m, l;
        tsplit(W0[(r + 64) * 576 + k], h, m, l);
        ws[W0H + i] = (short)h;
        ws[W0M + i] = (short)m;
        ws[W0L + i] = (short)l;
    } else if (i < 110592) {              // W1 gates 1..3: rows 64..255, stride 128, k<64
        int j = i - 98304;
        int r = j >> 6, k = j & 63;
        unsigned h, m, l;
        tsplit(W1[(r + 64) * 128 + k], h, m, l);
        ws[W1H + j] = (short)h;
        ws[W1M + j] = (short)m;
        ws[W1L + j] = (short)l;
    }
}

// ---------- kernel 2: fused QLSTM ----------
// LDS (34816 B -> 4 blocks/CU):
//   [0, 26112)      union: A split-planes ah/am/al [32][136] bf16 (3 x 8704 B)
//                          | zs [32][193] f32 (24704 B)
//   [26112, 34816)  hs [32][68] f32
__global__ __launch_bounds__(256) void qlstm_fused(
    const float* __restrict__ x,
    const float* __restrict__ b0,
    const float* __restrict__ th0,
    const float* __restrict__ g0,
    const float* __restrict__ be0,
    const float* __restrict__ b1,
    const float* __restrict__ th1,
    const float* __restrict__ g1,
    const float* __restrict__ be1,
    const short* __restrict__ wsp,
    float* __restrict__ out)
{
    __shared__ __align__(16) char lds[34816];
    short* ah = (short*)lds;                      // [32][136]
    short* am = ah + MB * AS_STRIDE;
    short* al = am + MB * AS_STRIDE;
    float* zs = (float*)lds;                      // [32][193] (aliases planes)
    float* hs = (float*)(lds + 26112);            // [32][68]

    const int tid = threadIdx.x;
    const long rowbase = (long)blockIdx.x * MB;

    float* out0 = out;                                      // h1      [T*B][64]
    float* out1 = out + (long)T_SEQ * B_BATCH * H_DIM;      // h0[-1]  [128][64]
    float* out2 = out1 + B_BATCH * H_DIM;                   // c0[-1]
    float* out3 = out2 + B_BATCH * H_DIM;                   // h1[-1]
    float* out4 = out3 + B_BATCH * H_DIM;                   // c1[-1]

    const int lane = tid & 63;
    const int wave = tid >> 6;
    const int ln   = lane & 15;   // MFMA m/n lane index
    const int quad = lane >> 4;   // MFMA k-group
    const int cw   = wave * 48;   // wave's N-column base (192 cols / 4 waves)

    // per-lane constants: lane == qubit index n in the fused phase
    const float bt0a = b0[64  + lane] + th0[64  + lane];   // gate 1
    const float bt0b = b0[128 + lane] + th0[128 + lane];   // gate 2
    const float bt0c = b0[192 + lane] + th0[192 + lane];   // gate 3
    const float bt1a = b1[64  + lane] + th1[64  + lane];
    const float bt1b = b1[128 + lane] + th1[128 + lane];
    const float bt1c = b1[192 + lane] + th1[192 + lane];
    const float g0v = g0[lane], be0v = be0[lane];
    const float g1v = g1[lane], be1v = be1[lane];

    // B plane row offsets (shorts) for this wave's 3 column-tiles
    int brow0[3], brow1[3];
    for (int nt = 0; nt < 3; ++nt) {
        int gc = cw + nt * 16 + ln;
        brow0[nt] = gc * 512;
        brow1[nt] = gc * 64;
    }

    // ------- GEMM1: z0[32][192] = x[32][512] . W0g^T, split planes, K chunks of 128
    f32x4 acc[2][3];
    for (int mt = 0; mt < 2; ++mt)
        for (int nt = 0; nt < 3; ++nt)
            acc[mt][nt] = (f32x4){0.f, 0.f, 0.f, 0.f};

    for (int kc = 0; kc < 512; kc += 128) {
        // stage + split x chunk [32][128] -> 3 bf16 planes (each element split once)
        for (int pass = 0; pass < 2; ++pass) {
            int e  = pass * 256 + tid;      // 0..511 covers 512*8 = 4096 elements
            int r  = e >> 4;                // row 0..31
            int k8 = (e & 15) << 3;         // col 0,8,...,120
            const float* xp = x + (rowbase + r) * 512 + kc + k8;
            float4 f0 = *(const float4*)xp;
            float4 f1 = *(const float4*)(xp + 4);
            uint4 Ph, Pm, Pl;
            tsplit2(f0.x, f0.y, Ph.x, Pm.x, Pl.x);
            tsplit2(f0.z, f0.w, Ph.y, Pm.y, Pl.y);
            tsplit2(f1.x, f1.y, Ph.z, Pm.z, Pl.z);
            tsplit2(f1.z, f1.w, Ph.w, Pm.w, Pl.w);
            int ao = r * AS_STRIDE + k8;
            *(uint4*)(ah + ao) = Ph;
            *(uint4*)(am + ao) = Pm;
            *(uint4*)(al + ao) = Pl;
        }
        __syncthreads();
        for (int k0 = 0; k0 < 128; k0 += 32) {
            int ka = k0 + quad * 8;
            bf16x8 Ah[2], Am[2], Al[2];
            for (int mt = 0; mt < 2; ++mt) {
                int ao = (mt * 16 + ln) * AS_STRIDE + ka;
                Ah[mt] = *(const bf16x8*)(ah + ao);
                Am[mt] = *(const bf16x8*)(am + ao);
                Al[mt] = *(const bf16x8*)(al + ao);
            }
            for (int nt = 0; nt < 3; ++nt) {
                int bo = brow0[nt] + kc + ka;
                bf16x8 Bh = *(const bf16x8*)(wsp + W0H + bo);
                bf16x8 Bm = *(const bf16x8*)(wsp + W0M + bo);
                bf16x8 Bl = *(const bf16x8*)(wsp + W0L + bo);
                for (int mt = 0; mt < 2; ++mt)
                    acc[mt][nt] = mfma6(Ah[mt], Am[mt], Al[mt], Bh, Bm, Bl, acc[mt][nt]);
            }
        }
        __syncthreads();   // plane reads done before next stage / zs overwrite
    }

    // epilogue: D[m][n]: col = lane&15, row = quad*4 + reg  [measured m89/m91]
    for (int mt = 0; mt < 2; ++mt)
        for (int nt = 0; nt < 3; ++nt)
            for (int i = 0; i < 4; ++i) {
                int row = mt * 16 + quad * 4 + i;
                int col = cw + nt * 16 + ln;
                zs[row * ZS_STRIDE + col] = acc[mt][nt][i];
            }
    __syncthreads();

    // ------- fused cumprod + gates + LayerNorm, layer 0 (one wave per row) -------
    for (int p = 0; p < 8; ++p) {
        int row = wave * 8 + p;
        const float* zr = zs + row * ZS_STRIDE;
        float c1 = cosf(zr[lane]        + bt0a);
        float c2 = cosf(zr[64  + lane]  + bt0b);
        float c3 = cosf(zr[128 + lane]  + bt0c);
        float q1 = scan_prod(c1, lane);
        float q2 = scan_prod(c2, lane);
        float q3 = scan_prod(c3, lane);
        float ig = acc_sigmoid(q1);
        float gg = tanhf(acc_sigmoid(q2));
        float og = acc_sigmoid(q3);
        float c  = ig * gg;
        float hv = og * tanhf(c);
        float mu = wave_sum(hv) * (1.0f / 64.0f);
        float d  = hv - mu;
        float var = wave_sum(d * d) * (1.0f / 64.0f);
        float rs  = rsqrtf(var + 1e-5f);
        float hl  = d * rs * g0v + be0v;
        hs[row * HS_STRIDE + lane] = hl;
        long tbrow = rowbase + row;
        if (tbrow >= LASTROW) {
            int bidx = (int)(tbrow - LASTROW);
            out1[bidx * 64 + lane] = hl;
            out2[bidx * 64 + lane] = c;
        }
    }
    __syncthreads();

    // ------- GEMM2: z1[32][192] = h0[32][64] . W1g^T, inline A-split, K=64 -------
    f32x4 acc2[2][3];
    for (int mt = 0; mt < 2; ++mt)
        for (int nt = 0; nt < 3; ++nt)
            acc2[mt][nt] = (f32x4){0.f, 0.f, 0.f, 0.f};
    for (int k0 = 0; k0 < 64; k0 += 32) {
        int ka = k0 + quad * 8;
        bf16x8 Ah[2], Am[2], Al[2];
        for (int mt = 0; mt < 2; ++mt) {
            const float* ptr = hs + (mt * 16 + ln) * HS_STRIDE + ka;
            float4 f0 = *(const float4*)ptr;
            float4 f1 = *(const float4*)(ptr + 4);
            uint4 Ph, Pm, Pl;
            tsplit2(f0.x, f0.y, Ph.x, Pm.x, Pl.x);
            tsplit2(f0.z, f0.w, Ph.y, Pm.y, Pl.y);
            tsplit2(f1.x, f1.y, Ph.z, Pm.z, Pl.z);
            tsplit2(f1.z, f1.w, Ph.w, Pm.w, Pl.w);
            Ah[mt] = __builtin_bit_cast(bf16x8, Ph);
            Am[mt] = __builtin_bit_cast(bf16x8, Pm);
            Al[mt] = __builtin_bit_cast(bf16x8, Pl);
        }
        for (int nt = 0; nt < 3; ++nt) {
            int bo = brow1[nt] + ka;
            bf16x8 Bh = *(const bf16x8*)(wsp + W1H + bo);
            bf16x8 Bm = *(const bf16x8*)(wsp + W1M + bo);
            bf16x8 Bl = *(const bf16x8*)(wsp + W1L + bo);
            for (int mt = 0; mt < 2; ++mt)
                acc2[mt][nt] = mfma6(Ah[mt], Am[mt], Al[mt], Bh, Bm, Bl, acc2[mt][nt]);
        }
    }
    // layer-0 zs fully consumed (barrier above); planes dead -> safe to write zs
    for (int mt = 0; mt < 2; ++mt)
        for (int nt = 0; nt < 3; ++nt)
            for (int i = 0; i < 4; ++i) {
                int row = mt * 16 + quad * 4 + i;
                int col = cw + nt * 16 + ln;
                zs[row * ZS_STRIDE + col] = acc2[mt][nt][i];
            }
    __syncthreads();

    // ------- fused cumprod + gates + LayerNorm, layer 1 -> out -------
    for (int p = 0; p < 8; ++p) {
        int row = wave * 8 + p;
        const float* zr = zs + row * ZS_STRIDE;
        float c1 = cosf(zr[lane]        + bt1a);
        float c2 = cosf(zr[64  + lane]  + bt1b);
        float c3 = cosf(zr[128 + lane]  + bt1c);
        float q1 = scan_prod(c1, lane);
        float q2 = scan_prod(c2, lane);
        float q3 = scan_prod(c3, lane);
        float ig = acc_sigmoid(q1);
        float gg = tanhf(acc_sigmoid(q2));
        float og = acc_sigmoid(q3);
        float c  = ig * gg;
        float hv = og * tanhf(c);
        float mu = wave_sum(hv) * (1.0f / 64.0f);
        float d  = hv - mu;
        float var = wave_sum(d * d) * (1.0f / 64.0f);
        float rs  = rsqrtf(var + 1e-5f);
        float hl  = d * rs * g1v + be1v;
        long tbrow = rowbase + row;
        out0[tbrow * 64 + lane] = hl;
        if (tbrow >= LASTROW) {
            int bidx = (int)(tbrow - LASTROW);
            out3[bidx * 64 + lane] = hl;
            out4[bidx * 64 + lane] = c;
        }
    }
}

extern "C" void kernel_launch(void* const* d_in, const int* in_sizes, int n_in,
                              void* d_out, int out_size, void* d_ws, size_t ws_size,
                              hipStream_t stream) {
    const float* x   = (const float*)d_in[0];
    const float* W0  = (const float*)d_in[1];
    const float* b0  = (const float*)d_in[2];
    const float* th0 = (const float*)d_in[3];
    const float* g0  = (const float*)d_in[4];
    const float* be0 = (const float*)d_in[5];
    const float* W1  = (const float*)d_in[6];
    const float* b1  = (const float*)d_in[7];
    const float* th1 = (const float*)d_in[8];
    const float* g1  = (const float*)d_in[9];
    const float* be1 = (const float*)d_in[10];
    short* wsp = (short*)d_ws;     // needs 663552 B

    presplit_w<<<dim3(432), dim3(256), 0, stream>>>(W0, W1, wsp);
    qlstm_fused<<<dim3(2048), dim3(256), 0, stream>>>(
        x, b0, th0, g0, be0, b1, th1, g1, be1, wsp, (float*)d_out);
}

// Round 6
// 358.783 us; speedup vs baseline: 1.1391x; 1.1391x over previous
//
#include <hip/hip_runtime.h>
#include <hip/hip_bf16.h>

typedef __attribute__((ext_vector_type(8))) short bf16x8;
typedef _Float16 f16x8 __attribute__((ext_vector_type(8)));
typedef __attribute__((ext_vector_type(4))) float f32x4;

#define T_SEQ   512
#define B_BATCH 128
#define H_DIM   64
#define MB      64               // rows (t*B+b) per block
#define AS_STRIDE 72             // halves per plane row (64 + 8 pad; 144B rows, 16B-mult)
#define ZS_STRIDE 193            // f32 per row of z half-tile (192 + 1 pad)
#define HS_STRIDE 68             // f32 per row of h tile (64 + 4 pad)
#define LASTROW ((T_SEQ - 1) * B_BATCH)   // 65408

// ws layout (ushorts): 3 planes each: HF=fp16(f), HB=bf16(f), LB=bf16(f-fp16(f))
#define W0HF 0
#define W0HB 98304
#define W0LB 196608
#define W1HF 294912
#define W1HB 307200
#define W1LB 319488
// total 331776 ushorts = 663552 B of d_ws

// hybrid split: f ~= hf + (f-hf); cross terms via bf16. residual ~2^-19|f| per product
__device__ __forceinline__ void splitH(float f, unsigned& hf, unsigned& hb, unsigned& lb) {
    _Float16 h = (_Float16)f;
    hf = (unsigned)__builtin_bit_cast(unsigned short, h);
    float r = f - (float)h;
    hb = (unsigned)__builtin_bit_cast(unsigned short, __float2bfloat16(f));
    lb = (unsigned)__builtin_bit_cast(unsigned short, __float2bfloat16(r));
}

// split 8 contiguous floats -> packed uint4 per plane
__device__ __forceinline__ void splitH8(const float* p, uint4& Pf, uint4& Pb, uint4& Pl) {
    float4 a = *(const float4*)p;
    float4 b = *(const float4*)(p + 4);
    float v[8] = {a.x, a.y, a.z, a.w, b.x, b.y, b.z, b.w};
    unsigned f[8], hb[8], lb[8];
#pragma unroll
    for (int i = 0; i < 8; ++i) splitH(v[i], f[i], hb[i], lb[i]);
    Pf = (uint4){f[0] | (f[1] << 16), f[2] | (f[3] << 16), f[4] | (f[5] << 16), f[6] | (f[7] << 16)};
    Pb = (uint4){hb[0] | (hb[1] << 16), hb[2] | (hb[3] << 16), hb[4] | (hb[5] << 16), hb[6] | (hb[7] << 16)};
    Pl = (uint4){lb[0] | (lb[1] << 16), lb[2] | (lb[3] << 16), lb[4] | (lb[5] << 16), lb[6] | (lb[7] << 16)};
}

// 3-product accumulate: hf*hf' (f16) + hb*lb' + lb*hb' (bf16)
__device__ __forceinline__ f32x4 mfma3(f16x8 af, bf16x8 ab, bf16x8 al,
                                       f16x8 bf, bf16x8 bb, bf16x8 bl, f32x4 c) {
    c = __builtin_amdgcn_mfma_f32_16x16x32_f16(af, bf, c, 0, 0, 0);
    c = __builtin_amdgcn_mfma_f32_16x16x32_bf16(ab, bl, c, 0, 0, 0);
    c = __builtin_amdgcn_mfma_f32_16x16x32_bf16(al, bb, c, 0, 0, 0);
    return c;
}

// accurate sigmoid: libm expf + rcp with one Newton step
__device__ __forceinline__ float acc_sigmoid(float x) {
    float e = expf(-x);
    float d = 1.0f + e;
    float r = __builtin_amdgcn_rcpf(d);
    r = r * (2.0f - d * r);
    return r;
}

// inclusive prefix-product across the 64-lane wave (6-step scan) [HW-verified r5]
__device__ __forceinline__ float scan_prod(float v, int lane) {
    for (int d = 1; d < 64; d <<= 1) {
        float t = __shfl_up(v, d);
        v *= (lane >= d) ? t : 1.0f;
    }
    return v;
}

__device__ __forceinline__ float wave_sum(float v) {
    for (int d = 1; d < 64; d <<= 1) v += __shfl_xor(v, d);
    return v;
}

// ---------- kernel 1: pre-split weights into d_ws ----------
__global__ __launch_bounds__(256) void presplit_w(const float* __restrict__ W0,
                                                  const float* __restrict__ W1,
                                                  unsigned short* __restrict__ ws) {
    int i = blockIdx.x * 256 + threadIdx.x;
    if (i < 98304) {                      // W0 gates 1..3: flat rows 64..255, stride 576
        int r = i >> 9, k = i & 511;
        unsigned hf, hb, lb;
        splitH(W0[(r + 64) * 576 + k], hf, hb, lb);
        ws[W0HF + i] = (unsigned short)hf;
        ws[W0HB + i] = (unsigned short)hb;
        ws[W0LB + i] = (unsigned short)lb;
    } else if (i < 110592) {              // W1 gates 1..3: rows 64..255, stride 128, k<64
        int j = i - 98304;
        int r = j >> 6, k = j & 63;
        unsigned hf, hb, lb;
        splitH(W1[(r + 64) * 128 + k], hf, hb, lb);
        ws[W1HF + j] = (unsigned short)hf;
        ws[W1HB + j] = (unsigned short)hb;
        ws[W1LB + j] = (unsigned short)lb;
    }
}

// ---------- kernel 2: fused QLSTM ----------
// LDS (45056 B -> 3 blocks/CU):
//   [0, 27648)      union: A planes hf/hb/lb [64][72] half (3 x 9216 B)
//                          | zs [32][193] f32 half-tile (24704 B)
//   [27648, 45056)  hs [64][68] f32
__global__ __launch_bounds__(256) void qlstm_fused(
    const float* __restrict__ x,
    const float* __restrict__ b0,
    const float* __restrict__ th0,
    const float* __restrict__ g0,
    const float* __restrict__ be0,
    const float* __restrict__ b1,
    const float* __restrict__ th1,
    const float* __restrict__ g1,
    const float* __restrict__ be1,
    const unsigned short* __restrict__ wsp,
    float* __restrict__ out)
{
    __shared__ __align__(16) char lds[45056];
    unsigned short* phf = (unsigned short*)lds;           // [64][72]
    unsigned short* phb = phf + MB * AS_STRIDE;
    unsigned short* plb = phb + MB * AS_STRIDE;
    float* zs = (float*)lds;                              // [32][193] (aliases planes)
    float* hs = (float*)(lds + 27648);                    // [64][68]

    const int tid = threadIdx.x;
    const long rowbase = (long)blockIdx.x * MB;

    float* out0 = out;                                      // h1      [T*B][64]
    float* out1 = out + (long)T_SEQ * B_BATCH * H_DIM;      // h0[-1]  [128][64]
    float* out2 = out1 + B_BATCH * H_DIM;                   // c0[-1]
    float* out3 = out2 + B_BATCH * H_DIM;                   // h1[-1]
    float* out4 = out3 + B_BATCH * H_DIM;                   // c1[-1]

    const int lane = tid & 63;
    const int wave = tid >> 6;
    const int ln   = lane & 15;   // MFMA m/n lane index
    const int quad = lane >> 4;   // MFMA k-group
    const int cw   = wave * 48;   // wave's N-column base (192 cols / 4 waves)

    // per-lane constants: lane == qubit index
    const float bt0a = b0[64  + lane] + th0[64  + lane];
    const float bt0b = b0[128 + lane] + th0[128 + lane];
    const float bt0c = b0[192 + lane] + th0[192 + lane];
    const float bt1a = b1[64  + lane] + th1[64  + lane];
    const float bt1b = b1[128 + lane] + th1[128 + lane];
    const float bt1c = b1[192 + lane] + th1[192 + lane];
    const float g0v = g0[lane], be0v = be0[lane];
    const float g1v = g1[lane], be1v = be1[lane];

    int brow0[3], brow1[3];
    for (int nt = 0; nt < 3; ++nt) {
        int gc = cw + nt * 16 + ln;
        brow0[nt] = gc * 512;
        brow1[nt] = gc * 64;
    }

    // ------- GEMM1: z0[64][192] = x[64][512] . W0g^T, hybrid split, K chunks of 64
    f32x4 acc[4][3];
    for (int mt = 0; mt < 4; ++mt)
        for (int nt = 0; nt < 3; ++nt)
            acc[mt][nt] = (f32x4){0.f, 0.f, 0.f, 0.f};

    for (int kc = 0; kc < 512; kc += 64) {
        // stage + split x chunk [64][64] -> 3 planes (each element split once/block)
        for (int it = 0; it < 2; ++it) {
            int e  = it * 256 + tid;        // 0..511 -> 512*8 = 4096 elements
            int r  = e >> 3;                // row 0..63
            int k8 = (e & 7) << 3;          // col 0,8,...,56
            uint4 Pf, Pb, Pl;
            splitH8(x + (rowbase + r) * 512 + kc + k8, Pf, Pb, Pl);
            int ao = r * AS_STRIDE + k8;
            *(uint4*)(phf + ao) = Pf;
            *(uint4*)(phb + ao) = Pb;
            *(uint4*)(plb + ao) = Pl;
        }
        __syncthreads();
        for (int k0 = 0; k0 < 64; k0 += 32) {
            int ka = k0 + quad * 8;
            f16x8  Af[4];
            bf16x8 Ab[4], Al[4];
            for (int mt = 0; mt < 4; ++mt) {
                int ao = (mt * 16 + ln) * AS_STRIDE + ka;
                Af[mt] = *(const f16x8*)(phf + ao);
                Ab[mt] = *(const bf16x8*)(phb + ao);
                Al[mt] = *(const bf16x8*)(plb + ao);
            }
            for (int nt = 0; nt < 3; ++nt) {
                int bo = brow0[nt] + kc + ka;
                f16x8  Bf = *(const f16x8*)(wsp + W0HF + bo);
                bf16x8 Bb = *(const bf16x8*)(wsp + W0HB + bo);
                bf16x8 Bl = *(const bf16x8*)(wsp + W0LB + bo);
                for (int mt = 0; mt < 4; ++mt)
                    acc[mt][nt] = mfma3(Af[mt], Ab[mt], Al[mt], Bf, Bb, Bl, acc[mt][nt]);
            }
        }
        __syncthreads();   // plane reads done before next stage / zs overwrite
    }

    // ------- layer 0: half-tiled epilogue + fused cumprod/gates/LN -------
    for (int h = 0; h < 2; ++h) {
        // epilogue: D[m][n]: col = lane&15, row = quad*4 + reg  [measured m89/m91]
        for (int mt2 = 0; mt2 < 2; ++mt2) {
            int mt = h * 2 + mt2;
            for (int nt = 0; nt < 3; ++nt)
                for (int i = 0; i < 4; ++i) {
                    int rowl = mt2 * 16 + quad * 4 + i;
                    int col  = cw + nt * 16 + ln;
                    zs[rowl * ZS_STRIDE + col] = acc[mt][nt][i];
                }
        }
        __syncthreads();
        for (int p = 0; p < 8; ++p) {
            int rowl = wave * 8 + p;
            const float* zr = zs + rowl * ZS_STRIDE;
            float c1 = cosf(zr[lane]        + bt0a);
            float c2 = cosf(zr[64  + lane]  + bt0b);
            float c3 = cosf(zr[128 + lane]  + bt0c);
            float q1 = scan_prod(c1, lane);
            float q2 = scan_prod(c2, lane);
            float q3 = scan_prod(c3, lane);
            float ig = acc_sigmoid(q1);
            float gg = tanhf(acc_sigmoid(q2));
            float og = acc_sigmoid(q3);
            float c  = ig * gg;
            float hv = og * tanhf(c);
            float mu = wave_sum(hv) * (1.0f / 64.0f);
            float d  = hv - mu;
            float var = wave_sum(d * d) * (1.0f / 64.0f);
            float rs  = rsqrtf(var + 1e-5f);
            float hl  = d * rs * g0v + be0v;
            int row = h * 32 + rowl;
            hs[row * HS_STRIDE + lane] = hl;
            long tbrow = rowbase + row;
            if (tbrow >= LASTROW) {
                int bidx = (int)(tbrow - LASTROW);
                out1[bidx * 64 + lane] = hl;
                out2[bidx * 64 + lane] = c;
            }
        }
        __syncthreads();
    }

    // ------- GEMM2: z1[64][192] = h0[64][64] . W1g^T, inline hybrid split, K=64 -------
    f32x4 acc2[4][3];
    for (int mt = 0; mt < 4; ++mt)
        for (int nt = 0; nt < 3; ++nt)
            acc2[mt][nt] = (f32x4){0.f, 0.f, 0.f, 0.f};
    for (int k0 = 0; k0 < 64; k0 += 32) {
        int ka = k0 + quad * 8;
        f16x8  Af[4];
        bf16x8 Ab[4], Al[4];
        for (int mt = 0; mt < 4; ++mt) {
            uint4 Pf, Pb, Pl;
            splitH8(hs + (mt * 16 + ln) * HS_STRIDE + ka, Pf, Pb, Pl);
            Af[mt] = __builtin_bit_cast(f16x8, Pf);
            Ab[mt] = __builtin_bit_cast(bf16x8, Pb);
            Al[mt] = __builtin_bit_cast(bf16x8, Pl);
        }
        for (int nt = 0; nt < 3; ++nt) {
            int bo = brow1[nt] + ka;
            f16x8  Bf = *(const f16x8*)(wsp + W1HF + bo);
            bf16x8 Bb = *(const bf16x8*)(wsp + W1HB + bo);
            bf16x8 Bl = *(const bf16x8*)(wsp + W1LB + bo);
            for (int mt = 0; mt < 4; ++mt)
                acc2[mt][nt] = mfma3(Af[mt], Ab[mt], Al[mt], Bf, Bb, Bl, acc2[mt][nt]);
        }
    }

    // ------- layer 1: half-tiled epilogue + fused phase -> outputs -------
    for (int h = 0; h < 2; ++h) {
        for (int mt2 = 0; mt2 < 2; ++mt2) {
            int mt = h * 2 + mt2;
            for (int nt = 0; nt < 3; ++nt)
                for (int i = 0; i < 4; ++i) {
                    int rowl = mt2 * 16 + quad * 4 + i;
                    int col  = cw + nt * 16 + ln;
                    zs[rowl * ZS_STRIDE + col] = acc2[mt][nt][i];
                }
        }
        __syncthreads();
        for (int p = 0; p < 8; ++p) {
            int rowl = wave * 8 + p;
            const float* zr = zs + rowl * ZS_STRIDE;
            float c1 = cosf(zr[lane]        + bt1a);
            float c2 = cosf(zr[64  + lane]  + bt1b);
            float c3 = cosf(zr[128 + lane]  + bt1c);
            float q1 = scan_prod(c1, lane);
            float q2 = scan_prod(c2, lane);
            float q3 = scan_prod(c3, lane);
            float ig = acc_sigmoid(q1);
            float gg = tanhf(acc_sigmoid(q2));
            float og = acc_sigmoid(q3);
            float c  = ig * gg;
            float hv = og * tanhf(c);
            float mu = wave_sum(hv) * (1.0f / 64.0f);
            float d  = hv - mu;
            float var = wave_sum(d * d) * (1.0f / 64.0f);
            float rs  = rsqrtf(var + 1e-5f);
            float hl  = d * rs * g1v + be1v;
            int row = h * 32 + rowl;
            long tbrow = rowbase + row;
            out0[tbrow * 64 + lane] = hl;
            if (tbrow >= LASTROW) {
                int bidx = (int)(tbrow - LASTROW);
                out3[bidx * 64 + lane] = hl;
                out4[bidx * 64 + lane] = c;
            }
        }
        if (h == 0) __syncthreads();   // zs reused by h=1 epilogue
    }
}

extern "C" void kernel_launch(void* const* d_in, const int* in_sizes, int n_in,
                              void* d_out, int out_size, void* d_ws, size_t ws_size,
                              hipStream_t stream) {
    const float* x   = (const float*)d_in[0];
    const float* W0  = (const float*)d_in[1];
    const float* b0  = (const float*)d_in[2];
    const float* th0 = (const float*)d_in[3];
    const float* g0  = (const float*)d_in[4];
    const float* be0 = (const float*)d_in[5];
    const float* W1  = (const float*)d_in[6];
    const float* b1  = (const float*)d_in[7];
    const float* th1 = (const float*)d_in[8];
    const float* g1  = (const float*)d_in[9];
    const float* be1 = (const float*)d_in[10];
    unsigned short* wsp = (unsigned short*)d_ws;   // needs 663552 B

    presplit_w<<<dim3(432), dim3(256), 0, stream>>>(W0, W1, wsp);
    qlstm_fused<<<dim3(1024), dim3(256), 0, stream>>>(
        x, b0, th0, g0, be0, b1, th1, g1, be1, wsp, (float*)d_out);
}